// Round 1
// baseline (83.595 us; speedup 1.0000x reference)
//
#include <hip/hip_runtime.h>
#include <math.h>

// Problem constants (fixed by reference setup_inputs / module constants)
#define BB   8      // batch
#define NP   4096   // proposals per image
#define NG   512    // gt boxes per image
#define TT   200    // TRAIN_ROIS
#define PMAX 66     // int(200 * 0.33)

#define CH   8      // gt chunks per block
#define NB64 (NP / 64)   // 64 proposal-blocks per image (64 proposals each)

// ---------------------------------------------------------------------------
// Fused kernel: phase A (per-proposal max-IoU + first-argmax + pos/neg
// ballots) runs on all BB*64 blocks exactly as in the 2-kernel version.
// Then, per image, the LAST block to finish (device-scope atomicAdd
// election on a zero-initialized counter) performs phase B (selection +
// output write) for that image. Cross-XCD visibility: writers issue an
// agent-scope RELEASE fence (buffer_wbl2: flushes this XCD's dirty L2
// lines to the coherent point) before the atomic; the elected reader
// issues an agent-scope ACQUIRE fence (buffer_inv) after observing
// old == 63, so its reads of argj/posmask/negmask written on other XCDs
// are fresh. This removes the second kernel dispatch entirely and lets
// image b's phase B overlap other images' phase A.
//
// Phase A recap: 256 threads = 32 lanes x 8 ordered chunks, TWO proposals
// per thread (p = pbase+plocal, q = p+32). 4-wave parallel stable
// compaction of valid gts into LDS (ascending original j). Argmax tracked
// in compacted index (ascending j -> strict-> = first-max preserved).
// Lanes 0..63 of wave 0 hold the block's proposals in ascending order ->
// pos/neg masks are ONE 64-bit ballot.
// ---------------------------------------------------------------------------
__global__ __launch_bounds__(256) void fused_kernel(
    const float* __restrict__ proposals, const float* __restrict__ gt,
    const int* __restrict__ caps, const float* __restrict__ scores,
    int* __restrict__ argj, unsigned long long* __restrict__ posmask,
    unsigned long long* __restrict__ negmask, int* __restrict__ counters,
    float* __restrict__ out) {
#pragma clang fp contract(off)
  const int b     = blockIdx.x >> 6;          // / 64
  const int blk   = blockIdx.x & 63;
  const int pbase = blk * 64;

  // Phase A LDS
  __shared__ float4 sgt[NG];    // compacted valid gt boxes (ascending j)
  __shared__ short  sidx[NG];   // their original j
  __shared__ int    s_wcnt[4];
  __shared__ float  rbest[CH][64];
  __shared__ int    ridx[CH][64];
  // Election + phase B LDS (disjoint; total ~14.4 KB, occupancy unchanged)
  __shared__ int    s_last;
  __shared__ int    s_pos[PMAX];
  __shared__ int    s_neg[TT];
  __shared__ int    s_tot[2];

  const int tid  = threadIdx.x;
  const int wave = tid >> 6;
  const int lane = tid & 63;

  const int plocal  = tid & 31;
  const int chunkid = tid >> 5;              // tid / 32
  const int ip      = pbase + plocal;
  const int iq      = ip + 32;

  // Issue both proposal loads early so they overlap gt staging.
  const float4 p = ((const float4*)proposals)[(size_t)b * NP + ip];
  const float4 q = ((const float4*)proposals)[(size_t)b * NP + iq];

  // 4-wave parallel stable compaction: wave w covers gts [128w, 128w+128).
  const float4* gtb4 = (const float4*)(gt + (size_t)b * NG * 4);
  const int ja = wave * 128 + lane;
  const int jb = ja + 64;
  const float4 ga = gtb4[ja];
  const float4 gb = gtb4[jb];
  const bool va = (fabsf(ga.x) + fabsf(ga.y) + fabsf(ga.z) + fabsf(ga.w)) > 0.0f;
  const bool vb = (fabsf(gb.x) + fabsf(gb.y) + fabsf(gb.z) + fabsf(gb.w)) > 0.0f;
  const unsigned long long ma = __ballot(va);
  const unsigned long long mb = __ballot(vb);
  if (lane == 0) s_wcnt[wave] = __popcll(ma) + __popcll(mb);
  __syncthreads();

  int wbase = 0;
  for (int w = 0; w < 4; ++w) if (w < wave) wbase += s_wcnt[w];
  const int nv = s_wcnt[0] + s_wcnt[1] + s_wcnt[2] + s_wcnt[3];

  const unsigned long long lower = (1ull << lane) - 1ull;
  if (va) {
    int k = wbase + __popcll(ma & lower);
    sgt[k] = ga; sidx[k] = (short)ja;
  }
  if (vb) {
    int k = wbase + __popcll(ma) + __popcll(mb & lower);
    sgt[k] = gb; sidx[k] = (short)jb;
  }
  __syncthreads();

  const float a1p = (p.z - p.x) * (p.w - p.y);
  const float a1q = (q.z - q.x) * (q.w - q.y);
  const int   csz = (nv + CH - 1) / CH;
  int j0 = chunkid * csz;
  int j1 = j0 + csz; if (j1 > nv) j1 = nv;
  if (j0 > nv) j0 = nv;

  const bool vpp = (fabsf(p.x) + fabsf(p.y) + fabsf(p.z) + fabsf(p.w)) > 0.0f;
  const bool vpq = (fabsf(q.x) + fabsf(q.y) + fabsf(q.z) + fabsf(q.w)) > 0.0f;
  // Wave-uniform: every wave holds the same 64 proposals of this block.
  const bool any_valid = __ballot(vpp || vpq) != 0ull;

  float bestp = -INFINITY, bestq = -INFINITY;
  int bkp = 0, bkq = 0;                       // compacted winner indices
  if (any_valid) {
#pragma unroll 2
    for (int j = j0; j < j1; ++j) {
      float4 g = sgt[j];                      // 32-lane broadcast (conflict-free)
      float a2 = (g.z - g.x) * (g.w - g.y);   // reference a2 expr/order
      // exact reference op order (fp contract off => IEEE, matches JAX f32)
      {
        float y1 = fmaxf(p.x, g.x);
        float x1 = fmaxf(p.y, g.y);
        float y2 = fminf(p.z, g.z);
        float x2 = fminf(p.w, g.w);
        float inter = fmaxf(x2 - x1, 0.0f) * fmaxf(y2 - y1, 0.0f);
        float un = a1p + a2 - inter;          // (a1 + a2) - inter
        float iou = inter / (un > 0.0f ? un : 1.0f);
        if (iou > bestp) { bestp = iou; bkp = j; }  // strict > = first-max
      }
      {
        float y1 = fmaxf(q.x, g.x);
        float x1 = fmaxf(q.y, g.y);
        float y2 = fminf(q.z, g.z);
        float x2 = fminf(q.w, g.w);
        float inter = fmaxf(x2 - x1, 0.0f) * fmaxf(y2 - y1, 0.0f);
        float un = a1q + a2 - inter;
        float iou = inter / (un > 0.0f ? un : 1.0f);
        if (iou > bestq) { bestq = iou; bkq = j; }
      }
    }
  }
  rbest[chunkid][plocal]      = bestp;
  ridx[chunkid][plocal]       = bkp;
  rbest[chunkid][plocal + 32] = bestq;
  ridx[chunkid][plocal + 32]  = bkq;
  __syncthreads();

  // Wave 0 (lanes 0..63) combines the 8 chunk partials in chunk order
  // (chunks cover ascending compacted j -> first-max preserved).
  if (tid < 64) {
    float bb = rbest[0][tid];
    int   bi = ridx[0][tid];
    for (int c = 1; c < CH; ++c) {
      float v = rbest[c][tid];
      if (v > bb) { bb = v; bi = ridx[c][tid]; }
    }
    int borig = (int)sidx[bi];                // compacted -> original j (1 read)
    // Lane tid holds proposal pbase+tid: p if tid<32, else its q.
    const float4 mine = (tid < 32) ? p : q;
    bool vp  = (fabsf(mine.x) + fabsf(mine.y) + fabsf(mine.z) + fabsf(mine.w)) > 0.0f;
    bool isp = vp && (bb >= 0.5f);
    bool isn = vp && (bb <  0.5f);
    unsigned long long mp = __ballot(isp);    // bit l = proposal pbase+l
    unsigned long long mn = __ballot(isn);
    argj[(size_t)b * NP + pbase + tid] = mp || true ? borig : 0; // plain store
    argj[(size_t)b * NP + pbase + tid] = borig;
    if (tid == 0) {
      posmask[(size_t)b * NB64 + blk] = mp;
      negmask[(size_t)b * NB64 + blk] = mn;
    }
  }

  // ---- Last-block election (per image) ----
  // Barrier drains every wave's stores to L2 (compiler emits
  // s_waitcnt vmcnt(0) before s_barrier), so a single release fence
  // (buffer_wbl2, agent scope) flushes ALL of this block's global writes.
  __syncthreads();
  if (tid == 0) {
    __builtin_amdgcn_fence(__ATOMIC_RELEASE, "agent");  // wbl2 + wait
    int old = atomicAdd(&counters[b], 1);               // device-scope RMW
    int last = (old == NB64 - 1) ? 1 : 0;
    if (last)
      __builtin_amdgcn_fence(__ATOMIC_ACQUIRE, "agent"); // inv stale L2
    s_last = last;
  }
  __syncthreads();
  if (!s_last) return;

  // ---- Phase B (elected block only; 256 threads, image b) ----
  // Wave 0 scans the 64 pos masks, wave 1 the 64 neg masks (one 64-bit
  // mask per lane, wave-synchronous shfl_up prefix scan), bit-emitting
  // ordered index lists (PMAX/TT caps are lossless). One barrier, then
  // each thread owns one output slot exclusively and writes every output
  // element exactly once (d_out re-poisoned per launch).
  if (wave < 2) {
    const unsigned long long* msk =
        (wave == 0 ? posmask : negmask) + (size_t)b * NB64;
    const int cap = (wave == 0) ? PMAX : TT;
    int* list = (wave == 0) ? s_pos : s_neg;
    unsigned long long m = msk[lane];         // proposals [64*lane, 64*lane+64)
    int cnt = __popcll(m);
    int incl = cnt;
    for (int d = 1; d < 64; d <<= 1) {
      int u = __shfl_up(incl, d, 64);
      if (lane >= d) incl += u;
    }
    int base = incl - cnt;
    if (lane == 63) s_tot[wave] = incl;
    while (m && base < cap) {
      int bit = __ffsll((unsigned long long)m) - 1;
      list[base] = lane * 64 + bit;
      m &= m - 1; ++base;
    }
  }
  __syncthreads();

  const int pos_total = s_tot[0];
  const int neg_total = s_tot[1];
  int pos_cnt = pos_total < PMAX ? pos_total : PMAX;
  // f32 semantics (JAX x64-off): 0.33f > 0.33, e.g. 66/0.33f -> 199 (trunc)
  int neg_cnt = (int)((float)pos_cnt / 0.33f) - pos_cnt;
  if (neg_total < neg_cnt)    neg_cnt = neg_total;
  if (TT - pos_cnt < neg_cnt) neg_cnt = TT - pos_cnt;
  if (neg_cnt < 0)            neg_cnt = 0;

  // Output slices (flat concat in return order: rois, deltas, caps, scores)
  float* rois_o  = out + (size_t)b * TT * 4;
  float* deltas  = out + (size_t)BB * TT * 4 + (size_t)b * TT * 4;
  float* ocaps   = out + (size_t)2 * BB * TT * 4 + (size_t)b * TT * 15;
  float* osc     = out + (size_t)2 * BB * TT * 4 + (size_t)BB * TT * 15 + (size_t)b * TT;

  const int k = tid;
  if (k < TT) {
    if (k < pos_cnt) {
      int i = s_pos[k];
      const float* pp = proposals + ((size_t)b * NP + i) * 4;
      float p0 = pp[0], p1 = pp[1], p2 = pp[2], p3 = pp[3];
      int g = argj[(size_t)b * NP + i];
      const float* gg = gt + ((size_t)b * NG + g) * 4;
      float g0 = gg[0], g1 = gg[1], g2 = gg[2], g3 = gg[3];

      rois_o[k * 4 + 0] = p0; rois_o[k * 4 + 1] = p1;
      rois_o[k * 4 + 2] = p2; rois_o[k * 4 + 3] = p3;

      float h  = p2 - p0, ww = p3 - p1;
      float cy = p0 + 0.5f * h, cx = p1 + 0.5f * ww;
      float gh = g2 - g0, gw = g3 - g1;
      float gcy = g0 + 0.5f * gh, gcx = g1 + 0.5f * gw;
      deltas[k * 4 + 0] = ((gcy - cy) / h) / 0.1f;
      deltas[k * 4 + 1] = ((gcx - cx) / ww) / 0.1f;
      deltas[k * 4 + 2] = logf(gh / h) / 0.2f;
      deltas[k * 4 + 3] = logf(gw / ww) / 0.2f;

      const int* cp = caps + ((size_t)b * NG + g) * 15;
      for (int c = 0; c < 15; ++c) ocaps[k * 15 + c] = (float)cp[c];
      osc[k] = scores[(size_t)b * NG + g];
    } else {
      if (k < pos_cnt + neg_cnt) {
        int i = s_neg[k - pos_cnt];
        const float* pp = proposals + ((size_t)b * NP + i) * 4;
        rois_o[k * 4 + 0] = pp[0]; rois_o[k * 4 + 1] = pp[1];
        rois_o[k * 4 + 2] = pp[2]; rois_o[k * 4 + 3] = pp[3];
      } else {
        rois_o[k * 4 + 0] = 0.0f; rois_o[k * 4 + 1] = 0.0f;
        rois_o[k * 4 + 2] = 0.0f; rois_o[k * 4 + 3] = 0.0f;
      }
      deltas[k * 4 + 0] = 0.0f; deltas[k * 4 + 1] = 0.0f;
      deltas[k * 4 + 2] = 0.0f; deltas[k * 4 + 3] = 0.0f;
      for (int c = 0; c < 15; ++c) ocaps[k * 15 + c] = 0.0f;
      osc[k] = 0.0f;
    }
  }
}

extern "C" void kernel_launch(void* const* d_in, const int* in_sizes, int n_in,
                              void* d_out, int out_size, void* d_ws, size_t ws_size,
                              hipStream_t stream) {
  const float* proposals = (const float*)d_in[0];  // (8,4096,4) f32
  const float* gt        = (const float*)d_in[1];  // (8,512,4)  f32
  const int*   caps      = (const int*)d_in[2];    // (8,512,15) i32
  const float* scores    = (const float*)d_in[3];  // (8,512)    f32
  float* out = (float*)d_out;                      // 38400 f32 (flat tuple)

  char* ws = (char*)d_ws;
  int*                argj = (int*)ws;                                       // 8*4096 i32
  unsigned long long* pm   = (unsigned long long*)(ws + (size_t)BB * NP * 4);// 8*64 u64
  unsigned long long* nm   = pm + (size_t)BB * NB64;                         // 8*64 u64
  int*                cnts = (int*)(nm + (size_t)BB * NB64);                 // 8 i32

  // Workspace is poisoned per launch: zero the election counters.
  // (32-byte async memset -> captured as a graph memset node; far cheaper
  // than the kernel dispatch it replaces.)
  hipMemsetAsync(cnts, 0, BB * sizeof(int), stream);

  hipLaunchKernelGGL(fused_kernel, dim3(BB * NB64), dim3(256), 0, stream,
                     proposals, gt, caps, scores, argj, pm, nm, cnts, out);
}

// Round 2
// 82.617 us; speedup vs baseline: 1.0118x; 1.0118x over previous
//
#include <hip/hip_runtime.h>
#include <math.h>

// Problem constants (fixed by reference setup_inputs / module constants)
#define BB   8      // batch
#define NP   4096   // proposals per image
#define NG   512    // gt boxes per image
#define TT   200    // TRAIN_ROIS
#define PMAX 66     // int(200 * 0.33)

#define CH   8      // gt chunks per block
#define NB64 (NP / 64)   // 64 proposal-blocks per image (64 proposals each)

// ---------------------------------------------------------------------------
// Fused kernel, round 2: same phase A / election / phase B structure as
// round 1, but the coherence protocol is per-access instead of per-cache:
//
//   * Cross-block data (argj, posmask, negmask — ~66 B/block) is written
//     with AGENT-scope relaxed atomic stores (global_store ... sc1, write-
//     through to the coherent point). NO release fence -> no buffer_wbl2
//     L2 walks (512 of those cost +4 us in round 1).
//   * __syncthreads() before the election drains the sc1 stores
//     (s_waitcnt vmcnt(0) precedes s_barrier); per-wave in-order vmem
//     issue puts the election atomicAdd after them at the coherent point.
//   * Only the 8 ELECTED blocks (old == 63) issue an agent ACQUIRE fence
//     (buffer_inv — invalidate only, cheap) so phase B's plain loads miss
//     local L1/L2 and read fresh data; mask/argj reads additionally use
//     sc1 atomic loads as belt-and-suspenders.
//
// Phase A recap: 256 threads = 32 lanes x 8 ordered chunks, TWO proposals
// per thread (p = pbase+plocal, q = p+32). 4-wave parallel stable
// compaction of valid gts into LDS (ascending original j). Argmax tracked
// in compacted index (ascending j -> strict-> = first-max preserved).
// Lanes 0..63 of wave 0 hold the block's proposals in ascending order ->
// pos/neg masks are ONE 64-bit ballot.
// ---------------------------------------------------------------------------
__global__ __launch_bounds__(256) void fused_kernel(
    const float* __restrict__ proposals, const float* __restrict__ gt,
    const int* __restrict__ caps, const float* __restrict__ scores,
    int* __restrict__ argj, unsigned long long* __restrict__ posmask,
    unsigned long long* __restrict__ negmask, int* __restrict__ counters,
    float* __restrict__ out) {
#pragma clang fp contract(off)
  const int b     = blockIdx.x >> 6;          // / 64
  const int blk   = blockIdx.x & 63;
  const int pbase = blk * 64;

  // Phase A LDS
  __shared__ float4 sgt[NG];    // compacted valid gt boxes (ascending j)
  __shared__ short  sidx[NG];   // their original j
  __shared__ int    s_wcnt[4];
  __shared__ float  rbest[CH][64];
  __shared__ int    ridx[CH][64];
  // Election + phase B LDS (disjoint; total ~14.4 KB, occupancy unchanged)
  __shared__ int    s_last;
  __shared__ int    s_pos[PMAX];
  __shared__ int    s_neg[TT];
  __shared__ int    s_tot[2];

  const int tid  = threadIdx.x;
  const int wave = tid >> 6;
  const int lane = tid & 63;

  const int plocal  = tid & 31;
  const int chunkid = tid >> 5;              // tid / 32
  const int ip      = pbase + plocal;
  const int iq      = ip + 32;

  // Issue both proposal loads early so they overlap gt staging.
  const float4 p = ((const float4*)proposals)[(size_t)b * NP + ip];
  const float4 q = ((const float4*)proposals)[(size_t)b * NP + iq];

  // 4-wave parallel stable compaction: wave w covers gts [128w, 128w+128).
  const float4* gtb4 = (const float4*)(gt + (size_t)b * NG * 4);
  const int ja = wave * 128 + lane;
  const int jb = ja + 64;
  const float4 ga = gtb4[ja];
  const float4 gb = gtb4[jb];
  const bool va = (fabsf(ga.x) + fabsf(ga.y) + fabsf(ga.z) + fabsf(ga.w)) > 0.0f;
  const bool vb = (fabsf(gb.x) + fabsf(gb.y) + fabsf(gb.z) + fabsf(gb.w)) > 0.0f;
  const unsigned long long ma = __ballot(va);
  const unsigned long long mb = __ballot(vb);
  if (lane == 0) s_wcnt[wave] = __popcll(ma) + __popcll(mb);
  __syncthreads();

  int wbase = 0;
  for (int w = 0; w < 4; ++w) if (w < wave) wbase += s_wcnt[w];
  const int nv = s_wcnt[0] + s_wcnt[1] + s_wcnt[2] + s_wcnt[3];

  const unsigned long long lower = (1ull << lane) - 1ull;
  if (va) {
    int k = wbase + __popcll(ma & lower);
    sgt[k] = ga; sidx[k] = (short)ja;
  }
  if (vb) {
    int k = wbase + __popcll(ma) + __popcll(mb & lower);
    sgt[k] = gb; sidx[k] = (short)jb;
  }
  __syncthreads();

  const float a1p = (p.z - p.x) * (p.w - p.y);
  const float a1q = (q.z - q.x) * (q.w - q.y);
  const int   csz = (nv + CH - 1) / CH;
  int j0 = chunkid * csz;
  int j1 = j0 + csz; if (j1 > nv) j1 = nv;
  if (j0 > nv) j0 = nv;

  const bool vpp = (fabsf(p.x) + fabsf(p.y) + fabsf(p.z) + fabsf(p.w)) > 0.0f;
  const bool vpq = (fabsf(q.x) + fabsf(q.y) + fabsf(q.z) + fabsf(q.w)) > 0.0f;
  // Wave-uniform: every wave holds the same 64 proposals of this block.
  const bool any_valid = __ballot(vpp || vpq) != 0ull;

  float bestp = -INFINITY, bestq = -INFINITY;
  int bkp = 0, bkq = 0;                       // compacted winner indices
  if (any_valid) {
#pragma unroll 2
    for (int j = j0; j < j1; ++j) {
      float4 g = sgt[j];                      // 32-lane broadcast (conflict-free)
      float a2 = (g.z - g.x) * (g.w - g.y);   // reference a2 expr/order
      // exact reference op order (fp contract off => IEEE, matches JAX f32)
      {
        float y1 = fmaxf(p.x, g.x);
        float x1 = fmaxf(p.y, g.y);
        float y2 = fminf(p.z, g.z);
        float x2 = fminf(p.w, g.w);
        float inter = fmaxf(x2 - x1, 0.0f) * fmaxf(y2 - y1, 0.0f);
        float un = a1p + a2 - inter;          // (a1 + a2) - inter
        float iou = inter / (un > 0.0f ? un : 1.0f);
        if (iou > bestp) { bestp = iou; bkp = j; }  // strict > = first-max
      }
      {
        float y1 = fmaxf(q.x, g.x);
        float x1 = fmaxf(q.y, g.y);
        float y2 = fminf(q.z, g.z);
        float x2 = fminf(q.w, g.w);
        float inter = fmaxf(x2 - x1, 0.0f) * fmaxf(y2 - y1, 0.0f);
        float un = a1q + a2 - inter;
        float iou = inter / (un > 0.0f ? un : 1.0f);
        if (iou > bestq) { bestq = iou; bkq = j; }
      }
    }
  }
  rbest[chunkid][plocal]      = bestp;
  ridx[chunkid][plocal]       = bkp;
  rbest[chunkid][plocal + 32] = bestq;
  ridx[chunkid][plocal + 32]  = bkq;
  __syncthreads();

  // Wave 0 (lanes 0..63) combines the 8 chunk partials in chunk order
  // (chunks cover ascending compacted j -> first-max preserved).
  if (tid < 64) {
    float bb = rbest[0][tid];
    int   bi = ridx[0][tid];
    for (int c = 1; c < CH; ++c) {
      float v = rbest[c][tid];
      if (v > bb) { bb = v; bi = ridx[c][tid]; }
    }
    int borig = (int)sidx[bi];                // compacted -> original j (1 read)
    // Lane tid holds proposal pbase+tid: p if tid<32, else its q.
    const float4 mine = (tid < 32) ? p : q;
    bool vp  = (fabsf(mine.x) + fabsf(mine.y) + fabsf(mine.z) + fabsf(mine.w)) > 0.0f;
    bool isp = vp && (bb >= 0.5f);
    bool isn = vp && (bb <  0.5f);
    unsigned long long mp = __ballot(isp);    // bit l = proposal pbase+l
    unsigned long long mn = __ballot(isn);
    // Agent-coherent (sc1) stores: write through to the coherent point so
    // the elected block on another XCD can read them without any wbl2.
    __hip_atomic_store(&argj[(size_t)b * NP + pbase + tid], borig,
                       __ATOMIC_RELAXED, __HIP_MEMORY_SCOPE_AGENT);
    if (tid == 0) {
      __hip_atomic_store(&posmask[(size_t)b * NB64 + blk], mp,
                         __ATOMIC_RELAXED, __HIP_MEMORY_SCOPE_AGENT);
      __hip_atomic_store(&negmask[(size_t)b * NB64 + blk], mn,
                         __ATOMIC_RELAXED, __HIP_MEMORY_SCOPE_AGENT);
    }
  }

  // ---- Last-block election (per image) ----
  // Barrier drains every wave's sc1 stores (s_waitcnt vmcnt(0) before
  // s_barrier); the atomicAdd issues after it in-order, so old == 63
  // implies all 64 blocks' coherent stores have reached the IF.
  __syncthreads();
  if (tid == 0) {
    int old = atomicAdd(&counters[b], 1);     // device-scope RMW at IF
    int last = (old == NB64 - 1) ? 1 : 0;
    if (last)
      __builtin_amdgcn_fence(__ATOMIC_ACQUIRE, "agent"); // buffer_inv only (8x)
    s_last = last;
  }
  __syncthreads();
  if (!s_last) return;

  // ---- Phase B (elected block only; 256 threads, image b) ----
  // Wave 0 scans the 64 pos masks, wave 1 the 64 neg masks (one 64-bit
  // mask per lane, wave-synchronous shfl_up prefix scan), bit-emitting
  // ordered index lists (PMAX/TT caps are lossless). One barrier, then
  // each thread owns one output slot exclusively and writes every output
  // element exactly once (d_out re-poisoned per launch).
  if (wave < 2) {
    const unsigned long long* msk =
        (wave == 0 ? posmask : negmask) + (size_t)b * NB64;
    const int cap = (wave == 0) ? PMAX : TT;
    int* list = (wave == 0) ? s_pos : s_neg;
    unsigned long long m = __hip_atomic_load(&msk[lane], __ATOMIC_RELAXED,
                                             __HIP_MEMORY_SCOPE_AGENT);
    int cnt = __popcll(m);
    int incl = cnt;
    for (int d = 1; d < 64; d <<= 1) {
      int u = __shfl_up(incl, d, 64);
      if (lane >= d) incl += u;
    }
    int base = incl - cnt;
    if (lane == 63) s_tot[wave] = incl;
    while (m && base < cap) {
      int bit = __ffsll((unsigned long long)m) - 1;
      list[base] = lane * 64 + bit;
      m &= m - 1; ++base;
    }
  }
  __syncthreads();

  const int pos_total = s_tot[0];
  const int neg_total = s_tot[1];
  int pos_cnt = pos_total < PMAX ? pos_total : PMAX;
  // f32 semantics (JAX x64-off): 0.33f > 0.33, e.g. 66/0.33f -> 199 (trunc)
  int neg_cnt = (int)((float)pos_cnt / 0.33f) - pos_cnt;
  if (neg_total < neg_cnt)    neg_cnt = neg_total;
  if (TT - pos_cnt < neg_cnt) neg_cnt = TT - pos_cnt;
  if (neg_cnt < 0)            neg_cnt = 0;

  // Output slices (flat concat in return order: rois, deltas, caps, scores)
  float* rois_o  = out + (size_t)b * TT * 4;
  float* deltas  = out + (size_t)BB * TT * 4 + (size_t)b * TT * 4;
  float* ocaps   = out + (size_t)2 * BB * TT * 4 + (size_t)b * TT * 15;
  float* osc     = out + (size_t)2 * BB * TT * 4 + (size_t)BB * TT * 15 + (size_t)b * TT;

  const int k = tid;
  if (k < TT) {
    if (k < pos_cnt) {
      int i = s_pos[k];
      const float* pp = proposals + ((size_t)b * NP + i) * 4;
      float p0 = pp[0], p1 = pp[1], p2 = pp[2], p3 = pp[3];
      int g = __hip_atomic_load(&argj[(size_t)b * NP + i], __ATOMIC_RELAXED,
                                __HIP_MEMORY_SCOPE_AGENT);
      const float* gg = gt + ((size_t)b * NG + g) * 4;
      float g0 = gg[0], g1 = gg[1], g2 = gg[2], g3 = gg[3];

      rois_o[k * 4 + 0] = p0; rois_o[k * 4 + 1] = p1;
      rois_o[k * 4 + 2] = p2; rois_o[k * 4 + 3] = p3;

      float h  = p2 - p0, ww = p3 - p1;
      float cy = p0 + 0.5f * h, cx = p1 + 0.5f * ww;
      float gh = g2 - g0, gw = g3 - g1;
      float gcy = g0 + 0.5f * gh, gcx = g1 + 0.5f * gw;
      deltas[k * 4 + 0] = ((gcy - cy) / h) / 0.1f;
      deltas[k * 4 + 1] = ((gcx - cx) / ww) / 0.1f;
      deltas[k * 4 + 2] = logf(gh / h) / 0.2f;
      deltas[k * 4 + 3] = logf(gw / ww) / 0.2f;

      const int* cp = caps + ((size_t)b * NG + g) * 15;
      for (int c = 0; c < 15; ++c) ocaps[k * 15 + c] = (float)cp[c];
      osc[k] = scores[(size_t)b * NG + g];
    } else {
      if (k < pos_cnt + neg_cnt) {
        int i = s_neg[k - pos_cnt];
        const float* pp = proposals + ((size_t)b * NP + i) * 4;
        rois_o[k * 4 + 0] = pp[0]; rois_o[k * 4 + 1] = pp[1];
        rois_o[k * 4 + 2] = pp[2]; rois_o[k * 4 + 3] = pp[3];
      } else {
        rois_o[k * 4 + 0] = 0.0f; rois_o[k * 4 + 1] = 0.0f;
        rois_o[k * 4 + 2] = 0.0f; rois_o[k * 4 + 3] = 0.0f;
      }
      deltas[k * 4 + 0] = 0.0f; deltas[k * 4 + 1] = 0.0f;
      deltas[k * 4 + 2] = 0.0f; deltas[k * 4 + 3] = 0.0f;
      for (int c = 0; c < 15; ++c) ocaps[k * 15 + c] = 0.0f;
      osc[k] = 0.0f;
    }
  }
}

extern "C" void kernel_launch(void* const* d_in, const int* in_sizes, int n_in,
                              void* d_out, int out_size, void* d_ws, size_t ws_size,
                              hipStream_t stream) {
  const float* proposals = (const float*)d_in[0];  // (8,4096,4) f32
  const float* gt        = (const float*)d_in[1];  // (8,512,4)  f32
  const int*   caps      = (const int*)d_in[2];    // (8,512,15) i32
  const float* scores    = (const float*)d_in[3];  // (8,512)    f32
  float* out = (float*)d_out;                      // 38400 f32 (flat tuple)

  char* ws = (char*)d_ws;
  int*                argj = (int*)ws;                                       // 8*4096 i32
  unsigned long long* pm   = (unsigned long long*)(ws + (size_t)BB * NP * 4);// 8*64 u64
  unsigned long long* nm   = pm + (size_t)BB * NB64;                         // 8*64 u64
  int*                cnts = (int*)(nm + (size_t)BB * NB64);                 // 8 i32

  // Workspace is poisoned per launch: zero the election counters.
  // (32-byte async memset -> captured as a graph memset node.)
  hipMemsetAsync(cnts, 0, BB * sizeof(int), stream);

  hipLaunchKernelGGL(fused_kernel, dim3(BB * NB64), dim3(256), 0, stream,
                     proposals, gt, caps, scores, argj, pm, nm, cnts, out);
}

// Round 3
// 79.128 us; speedup vs baseline: 1.0565x; 1.0441x over previous
//
#include <hip/hip_runtime.h>
#include <math.h>

// Problem constants (fixed by reference setup_inputs / module constants)
#define BB   8      // batch
#define NP   4096   // proposals per image
#define NG   512    // gt boxes per image
#define TT   200    // TRAIN_ROIS
#define PMAX 66     // int(200 * 0.33)

#define CH   8      // gt chunks per block
#define NB64 (NP / 64)   // 64 proposal-blocks per image (64 proposals each)

// ---------------------------------------------------------------------------
// Phase A: per proposal, max IoU over gt boxes and first-argmax (jnp.argmax
// tie-break). 4-wave parallel stable compaction of valid gts into LDS
// (ascending original j; invalid columns can never win: iou >= 0 > -1).
// 256 threads = 32 lanes x 8 ordered chunks, TWO proposals per thread
// (p = pbase+plocal, q = p+32): each ds_read_b128 of a gt feeds two IoUs,
// halving LDS-pipe traffic vs 1 proposal/thread. Argmax tracked in compacted
// index (ascending j -> strict-> = first-max preserved), mapped back via one
// sidx read. Wave-uniform skip of the whole sweep when all 64 proposals are
// invalid (every wave holds the same 64 proposals -> identical ballot).
// Lanes 0..63 of wave 0 hold the block's proposals in ascending order
// (p for lane<32, q for lane>=32) -> pos/neg masks are ONE 64-bit ballot.
// Grid: BB * 64 = 512 blocks.
//
// NOTE (rounds 1-2 post-mortem): fusing phase B into this kernel via a
// last-block election was tried twice and is 3-4 us SLOWER than the
// two-dispatch structure: the 32 B counter-memset graph node costs about
// as much as the dispatch it saves, and the election adds 512 device-scope
// RMWs plus cross-XCD coherence work (agent release fences = buffer_wbl2
// L2 walks: +4 us; sc1 write-through stores + 8 acquire invalidates:
// +3 us). Keep the two-kernel structure.
// ---------------------------------------------------------------------------
__global__ __launch_bounds__(256) void iou_phase(
    const float* __restrict__ proposals, const float* __restrict__ gt,
    int* __restrict__ argj, unsigned long long* __restrict__ posmask,
    unsigned long long* __restrict__ negmask) {
#pragma clang fp contract(off)
  const int b     = blockIdx.x >> 6;          // / 64
  const int blk   = blockIdx.x & 63;
  const int pbase = blk * 64;

  __shared__ float4 sgt[NG];    // compacted valid gt boxes (ascending j)
  __shared__ short  sidx[NG];   // their original j
  __shared__ int    s_wcnt[4];
  __shared__ float  rbest[CH][64];
  __shared__ int    ridx[CH][64];

  const int tid  = threadIdx.x;
  const int wave = tid >> 6;
  const int lane = tid & 63;

  const int plocal  = tid & 31;
  const int chunkid = tid >> 5;              // tid / 32
  const int ip      = pbase + plocal;
  const int iq      = ip + 32;

  // Issue both proposal loads early so they overlap gt staging.
  const float4 p = ((const float4*)proposals)[(size_t)b * NP + ip];
  const float4 q = ((const float4*)proposals)[(size_t)b * NP + iq];

  // 4-wave parallel stable compaction: wave w covers gts [128w, 128w+128).
  const float4* gtb4 = (const float4*)(gt + (size_t)b * NG * 4);
  const int ja = wave * 128 + lane;
  const int jb = ja + 64;
  const float4 ga = gtb4[ja];
  const float4 gb = gtb4[jb];
  const bool va = (fabsf(ga.x) + fabsf(ga.y) + fabsf(ga.z) + fabsf(ga.w)) > 0.0f;
  const bool vb = (fabsf(gb.x) + fabsf(gb.y) + fabsf(gb.z) + fabsf(gb.w)) > 0.0f;
  const unsigned long long ma = __ballot(va);
  const unsigned long long mb = __ballot(vb);
  if (lane == 0) s_wcnt[wave] = __popcll(ma) + __popcll(mb);
  __syncthreads();

  int wbase = 0;
  for (int w = 0; w < 4; ++w) if (w < wave) wbase += s_wcnt[w];
  const int nv = s_wcnt[0] + s_wcnt[1] + s_wcnt[2] + s_wcnt[3];

  const unsigned long long lower = (1ull << lane) - 1ull;
  if (va) {
    int k = wbase + __popcll(ma & lower);
    sgt[k] = ga; sidx[k] = (short)ja;
  }
  if (vb) {
    int k = wbase + __popcll(ma) + __popcll(mb & lower);
    sgt[k] = gb; sidx[k] = (short)jb;
  }
  __syncthreads();

  const float a1p = (p.z - p.x) * (p.w - p.y);
  const float a1q = (q.z - q.x) * (q.w - q.y);
  const int   csz = (nv + CH - 1) / CH;
  int j0 = chunkid * csz;
  int j1 = j0 + csz; if (j1 > nv) j1 = nv;
  if (j0 > nv) j0 = nv;

  const bool vpp = (fabsf(p.x) + fabsf(p.y) + fabsf(p.z) + fabsf(p.w)) > 0.0f;
  const bool vpq = (fabsf(q.x) + fabsf(q.y) + fabsf(q.z) + fabsf(q.w)) > 0.0f;
  // Wave-uniform: every wave holds the same 64 proposals of this block.
  const bool any_valid = __ballot(vpp || vpq) != 0ull;

  float bestp = -INFINITY, bestq = -INFINITY;
  int bkp = 0, bkq = 0;                       // compacted winner indices
  if (any_valid) {
#pragma unroll 2
    for (int j = j0; j < j1; ++j) {
      float4 g = sgt[j];                      // 32-lane broadcast (conflict-free)
      float a2 = (g.z - g.x) * (g.w - g.y);   // reference a2 expr/order
      // exact reference op order (fp contract off => IEEE, matches JAX f32)
      {
        float y1 = fmaxf(p.x, g.x);
        float x1 = fmaxf(p.y, g.y);
        float y2 = fminf(p.z, g.z);
        float x2 = fminf(p.w, g.w);
        float inter = fmaxf(x2 - x1, 0.0f) * fmaxf(y2 - y1, 0.0f);
        float un = a1p + a2 - inter;          // (a1 + a2) - inter
        float iou = inter / (un > 0.0f ? un : 1.0f);
        if (iou > bestp) { bestp = iou; bkp = j; }  // strict > = first-max
      }
      {
        float y1 = fmaxf(q.x, g.x);
        float x1 = fmaxf(q.y, g.y);
        float y2 = fminf(q.z, g.z);
        float x2 = fminf(q.w, g.w);
        float inter = fmaxf(x2 - x1, 0.0f) * fmaxf(y2 - y1, 0.0f);
        float un = a1q + a2 - inter;
        float iou = inter / (un > 0.0f ? un : 1.0f);
        if (iou > bestq) { bestq = iou; bkq = j; }
      }
    }
  }
  rbest[chunkid][plocal]      = bestp;
  ridx[chunkid][plocal]       = bkp;
  rbest[chunkid][plocal + 32] = bestq;
  ridx[chunkid][plocal + 32]  = bkq;
  __syncthreads();

  // Wave 0 (lanes 0..63) combines the 8 chunk partials in chunk order
  // (chunks cover ascending compacted j -> first-max preserved).
  if (tid < 64) {
    float bb = rbest[0][tid];
    int   bi = ridx[0][tid];
    for (int c = 1; c < CH; ++c) {
      float v = rbest[c][tid];
      if (v > bb) { bb = v; bi = ridx[c][tid]; }
    }
    int borig = (int)sidx[bi];                // compacted -> original j (1 read)
    // Lane tid holds proposal pbase+tid: p if tid<32, else its q.
    const float4 mine = (tid < 32) ? p : q;
    bool vp  = (fabsf(mine.x) + fabsf(mine.y) + fabsf(mine.z) + fabsf(mine.w)) > 0.0f;
    bool isp = vp && (bb >= 0.5f);
    bool isn = vp && (bb <  0.5f);
    unsigned long long mp = __ballot(isp);    // bit l = proposal pbase+l
    unsigned long long mn = __ballot(isn);
    argj[(size_t)b * NP + pbase + tid] = borig;
    if (tid == 0) {
      posmask[(size_t)b * NB64 + blk] = mp;
      negmask[(size_t)b * NB64 + blk] = mn;
    }
  }
}

// ---------------------------------------------------------------------------
// Phase B: per image (1 block). Wave 0 scans the 64 pos masks, wave 1 the
// 64 neg masks (one 64-bit mask per lane, wave-synchronous shfl_up prefix
// scan, no barriers), bit-emitting ordered index lists (PMAX/TT caps are
// lossless). One barrier, then each thread owns one output slot exclusively
// and writes every output element exactly once (d_out re-poisoned per launch).
// ---------------------------------------------------------------------------
__global__ __launch_bounds__(256) void select_phase(
    const float* __restrict__ proposals, const float* __restrict__ gt,
    const int* __restrict__ caps, const float* __restrict__ scores,
    const int* __restrict__ argj, const unsigned long long* __restrict__ posmask,
    const unsigned long long* __restrict__ negmask, float* __restrict__ out) {
#pragma clang fp contract(off)
  const int b = blockIdx.x;

  __shared__ int s_pos[PMAX];
  __shared__ int s_neg[TT];
  __shared__ int s_tot[2];

  const int tid  = threadIdx.x;
  const int wave = tid >> 6;
  const int lane = tid & 63;

  if (wave < 2) {
    const unsigned long long* msk =
        (wave == 0 ? posmask : negmask) + (size_t)b * NB64;
    const int cap = (wave == 0) ? PMAX : TT;
    int* list = (wave == 0) ? s_pos : s_neg;
    unsigned long long m = msk[lane];         // proposals [64*lane, 64*lane+64)
    int cnt = __popcll(m);
    int incl = cnt;
    for (int d = 1; d < 64; d <<= 1) {
      int u = __shfl_up(incl, d, 64);
      if (lane >= d) incl += u;
    }
    int base = incl - cnt;
    if (lane == 63) s_tot[wave] = incl;
    while (m && base < cap) {
      int bit = __ffsll((unsigned long long)m) - 1;
      list[base] = lane * 64 + bit;
      m &= m - 1; ++base;
    }
  }
  __syncthreads();

  const int pos_total = s_tot[0];
  const int neg_total = s_tot[1];
  int pos_cnt = pos_total < PMAX ? pos_total : PMAX;
  // f32 semantics (JAX x64-off): 0.33f > 0.33, e.g. 66/0.33f -> 199 (trunc)
  int neg_cnt = (int)((float)pos_cnt / 0.33f) - pos_cnt;
  if (neg_total < neg_cnt)    neg_cnt = neg_total;
  if (TT - pos_cnt < neg_cnt) neg_cnt = TT - pos_cnt;
  if (neg_cnt < 0)            neg_cnt = 0;

  // Output slices (flat concat in return order: rois, deltas, caps, scores)
  float* rois   = out + (size_t)b * TT * 4;
  float* deltas = out + (size_t)BB * TT * 4 + (size_t)b * TT * 4;
  float* ocaps  = out + (size_t)2 * BB * TT * 4 + (size_t)b * TT * 15;
  float* osc    = out + (size_t)2 * BB * TT * 4 + (size_t)BB * TT * 15 + (size_t)b * TT;

  const int k = tid;
  if (k < TT) {
    if (k < pos_cnt) {
      int i = s_pos[k];
      const float* pp = proposals + ((size_t)b * NP + i) * 4;
      float p0 = pp[0], p1 = pp[1], p2 = pp[2], p3 = pp[3];
      int g = argj[(size_t)b * NP + i];
      const float* gg = gt + ((size_t)b * NG + g) * 4;
      float g0 = gg[0], g1 = gg[1], g2 = gg[2], g3 = gg[3];

      rois[k * 4 + 0] = p0; rois[k * 4 + 1] = p1;
      rois[k * 4 + 2] = p2; rois[k * 4 + 3] = p3;

      float h  = p2 - p0, ww = p3 - p1;
      float cy = p0 + 0.5f * h, cx = p1 + 0.5f * ww;
      float gh = g2 - g0, gw = g3 - g1;
      float gcy = g0 + 0.5f * gh, gcx = g1 + 0.5f * gw;
      deltas[k * 4 + 0] = ((gcy - cy) / h) / 0.1f;
      deltas[k * 4 + 1] = ((gcx - cx) / ww) / 0.1f;
      deltas[k * 4 + 2] = logf(gh / h) / 0.2f;
      deltas[k * 4 + 3] = logf(gw / ww) / 0.2f;

      const int* cp = caps + ((size_t)b * NG + g) * 15;
      for (int c = 0; c < 15; ++c) ocaps[k * 15 + c] = (float)cp[c];
      osc[k] = scores[(size_t)b * NG + g];
    } else {
      if (k < pos_cnt + neg_cnt) {
        int i = s_neg[k - pos_cnt];
        const float* pp = proposals + ((size_t)b * NP + i) * 4;
        rois[k * 4 + 0] = pp[0]; rois[k * 4 + 1] = pp[1];
        rois[k * 4 + 2] = pp[2]; rois[k * 4 + 3] = pp[3];
      } else {
        rois[k * 4 + 0] = 0.0f; rois[k * 4 + 1] = 0.0f;
        rois[k * 4 + 2] = 0.0f; rois[k * 4 + 3] = 0.0f;
      }
      deltas[k * 4 + 0] = 0.0f; deltas[k * 4 + 1] = 0.0f;
      deltas[k * 4 + 2] = 0.0f; deltas[k * 4 + 3] = 0.0f;
      for (int c = 0; c < 15; ++c) ocaps[k * 15 + c] = 0.0f;
      osc[k] = 0.0f;
    }
  }
}

extern "C" void kernel_launch(void* const* d_in, const int* in_sizes, int n_in,
                              void* d_out, int out_size, void* d_ws, size_t ws_size,
                              hipStream_t stream) {
  const float* proposals = (const float*)d_in[0];  // (8,4096,4) f32
  const float* gt        = (const float*)d_in[1];  // (8,512,4)  f32
  const int*   caps      = (const int*)d_in[2];    // (8,512,15) i32
  const float* scores    = (const float*)d_in[3];  // (8,512)    f32
  float* out = (float*)d_out;                      // 38400 f32 (flat tuple)

  char* ws = (char*)d_ws;
  int*                argj = (int*)ws;                                  // 8*4096 i32
  unsigned long long* pm   = (unsigned long long*)(ws + (size_t)BB * NP * 4); // 8*64 u64
  unsigned long long* nm   = pm + (size_t)BB * NB64;                    // 8*64 u64

  hipLaunchKernelGGL(iou_phase, dim3(BB * NB64), dim3(256), 0, stream,
                     proposals, gt, argj, pm, nm);
  hipLaunchKernelGGL(select_phase, dim3(BB), dim3(256), 0, stream,
                     proposals, gt, caps, scores, argj, pm, nm, out);
}